// Round 7
// baseline (1484.859 us; speedup 1.0000x reference)
//
#include <hip/hip_runtime.h>
#include <hip/hip_bf16.h>

// CGCNN forward, MFMA conv GEMM (R15).
//   g[e,:] = [x[n(e)] | x[nb(e)] | bond(e)] @ Wf + b  (K=169 pad 192, N=128)
// R15 vs R14: 6 rounds established that hipcc sinks loads to their uses and
// re-serializes every structural prefetch (R14: VGPR forced DOWN to 64,
// loads serial, 128us). R15 makes wide issue semantically mandatory:
//   - 18 named A-fragments loaded, then pinned by ONE empty asm volatile
//     reading/writing all 18 -> compiler must issue all loads back-to-back
//     and emit a single batched vmcnt wait (latency paid once/supertile,
//     not ~9x serial).
//   - 8 waves x 512 thr, one 16-col N-tile/wave -> Bf=24 VGPR; forced
//     live-set ~120 fits the allocator's natural 128-reg target.
//   - loop body, #pragma unroll 1 (unrolled bodies provoke regalloc spill
//     pathologies, R11-R13).
//   - nbr indices prefetched 1 supertile ahead (wait overlaps prev iter).
//   - ACT: R12-verified h-split (2 waves/atom-row, pbuf combine), raw
//     lgkm-only barriers.
// Canary: VGPR 120-135 + WRITE 16.5MB(ACT)/1MB(stats). VGPR<=100 => pin
// failed; WRITE high => spill.
// R7 LDS-staging fallback kept for ws_size < 108.5 MB.

#define NATOM 60000
#define MNBR  12
#define F0D   92
#define FBD   41
#define FD    64
#define F2D   128
#define NCRY  2000
#define HD    128
#define NSUP  15000          // 720000 edges / 48
#define GS    132            // gbuf row stride (floats)
#define CGRID 3000           // conv grid; NSUP/CGRID == 5 exactly

// ws layout (float units)
#define OFF_X      0ull          // 3,840,000 f32
#define OFF_XH     3840000ull    // 3,840,000 u16
#define OFF_SUMMED 5760000ull    // 3,840,000 f32
#define OFF_STATS  9600000ull    // sum1[128] sq1[128] sum2[64] sq2[64]
#define OFF_CRYS   9600384ull
#define OFF_CNT    9728384ull
#define OFF_WCONV  9730384ull    // 80,833 f32
#define OFF_WBF    9811220ull    // 73,728 u16 = 36,864 f slots
#define OFF_FLAG   9848084ull
#define WS_NEED_BYTES (9848085ull * 4ull)
#define OFF_BPAD   9848088ull    // 34,560,000 u16 = 17,280,000 f slots (16B aligned)
#define WS_FULL_BYTES ((OFF_BPAD + 17280000ull) * 4ull)   // 108,512,352

// offsets inside wconv
#define W_EMB_O  0
#define B_EMB_O  5888
#define W_FULL_O 5952
#define B_FULL_O 70848
#define G1_O     71232
#define BE1_O    71616
#define G2_O     72000
#define BE2_O    72192
#define W_FC_O   72384
#define B_FC_O   80576
#define W_OUT_O  80704
#define B_OUT_O  80832
#define WC_TOTAL 80833

typedef unsigned short u16;
typedef __attribute__((ext_vector_type(8))) short bf16x8;
typedef __attribute__((ext_vector_type(4))) float f32x4;

__device__ __forceinline__ float bf2f(u16 u){
  union { unsigned int i; float f; } v; v.i = ((unsigned int)u) << 16; return v.f;
}
__device__ __forceinline__ u16 f2bf(float f){
  union { float f; unsigned int i; } v; v.f = f;
  unsigned int x = v.i;
  return (u16)((x + 0x7FFFu + ((x >> 16) & 1u)) >> 16);
}
__device__ __forceinline__ float softplusf_(float x){
  return fmaxf(x, 0.f) + log1pf(expf(-fabsf(x)));
}
__device__ __forceinline__ float softplus_fast(float x){
  return fmaxf(x, 0.f) + __logf(1.f + __expf(-fabsf(x)));
}
__device__ __forceinline__ float sigmoid_fast(float x){
  return __builtin_amdgcn_rcpf(1.f + __expf(-x));
}

__global__ __launch_bounds__(64) void detect_kernel(
    const u16* __restrict__ data, int* __restrict__ flag){
  int tid = threadIdx.x;
  float v = bf2f(data[tid * 2]);
  float av = fabsf(v);
  bool sane = (av > 1e-6f) && (av < 100.f);
  unsigned long long m = __ballot(sane);
  if (tid == 0) *flag = (__popcll(m) >= 32) ? 1 : 0;
}

struct CvtArgs {
  const void* src[12];
  int start[13];
};

__global__ __launch_bounds__(256) void cvt_all_kernel(
    CvtArgs a, float* __restrict__ dst, const int* __restrict__ flag){
  int i = blockIdx.x * 256 + threadIdx.x;
  if (i >= WC_TOTAL) return;
  int r = 0;
  while (i >= a.start[r + 1]) r++;
  int rel = i - a.start[r];
  if (*flag) dst[i] = bf2f(((const u16*)a.src[r])[rel]);
  else       dst[i] = ((const float*)a.src[r])[rel];
}

__global__ __launch_bounds__(256) void build_bfrag(
    const float* __restrict__ wfull, u16* __restrict__ wbf){
  int t = blockIdx.x * 256 + threadIdx.x;
  if (t >= 3 * 6 * 8 * 64) return;
  int lane = t & 63, nt = (t >> 6) & 7, c = (t >> 9) % 6, layer = t / 3072;
  int q = lane >> 4, nloc = lane & 15;
  u16 vals[8];
  #pragma unroll
  for (int i = 0; i < 8; i++){
    int k = c * 32 + q * 8 + i;
    float v = (k < 169) ? wfull[layer * 169 * F2D + k * F2D + nt * 16 + nloc] : 0.f;
    vals[i] = f2bf(v);
  }
  *(uint4*)&wbf[(size_t)t * 8] = *(uint4*)vals;
}

// One-time repack ROW-MAJOR (R8-verified): bond_pad[e][0..47] = bf16(bond),
// zero for k>=41. Matches conv's direct per-lane b128 loads.
__global__ __launch_bounds__(256) void bond_prep(
    const void* __restrict__ nbr_fea, u16* __restrict__ bond_pad,
    const int* __restrict__ flag){
  __shared__ __align__(16) char sm[7872];
  u16*   lb_u = (u16*)sm;
  float* lb_f = (float*)sm;
  int s = blockIdx.x, tid = threadIdx.x;
  const int isbf = *flag;
  if (isbf){
    const uint4* src = (const uint4*)((const u16*)nbr_fea + (size_t)s * 1968);
    if (tid < 246) ((uint4*)sm)[tid] = src[tid];
  } else {
    const uint4* src = (const uint4*)((const float*)nbr_fea + (size_t)s * 1968);
    for (int t = tid; t < 492; t += 256) ((uint4*)sm)[t] = src[t];
  }
  __syncthreads();
  uint4* outv = (uint4*)(bond_pad + (size_t)s * 2304);
  for (int slot = tid; slot < 288; slot += 256){
    int el = slot / 6, jj = slot - el * 6;
    u16 v[8];
    #pragma unroll
    for (int i = 0; i < 8; i++){
      int k = jj * 8 + i;
      v[i] = (k < FBD) ? (isbf ? lb_u[el * FBD + k] : f2bf(lb_f[el * FBD + k])) : (u16)0;
    }
    outv[slot] = *(uint4*)v;
  }
}

__global__ __launch_bounds__(256) void embed_kernel(
    const void* __restrict__ atom_fea, const float* __restrict__ W_emb,
    const float* __restrict__ b_emb, float* __restrict__ x,
    u16* __restrict__ xh, const int* __restrict__ flag){
  int tid = threadIdx.x;
  int n = blockIdx.x * 4 + (tid >> 6);
  int f = tid & 63;
  float acc = b_emb[f];
  if (*flag){
    const u16* arow = (const u16*)atom_fea + n * F0D;
    for (int k = 0; k < F0D; k++)
      acc = fmaf(bf2f(arow[k]), W_emb[k * FD + f], acc);
  } else {
    const float* arow = (const float*)atom_fea + n * F0D;
    for (int k = 0; k < F0D; k++)
      acc = fmaf(arow[k], W_emb[k * FD + f], acc);
  }
  x[n * FD + f] = acc;
  xh[n * FD + f] = f2bf(acc);
}

// ---------------------------------------------------------------------------
// R15: batched-issue conv pass. 512 thr / 8 waves; wave wv owns N-cols
// [wv*16, wv*16+16). Loop over 5 supertiles (unroll 1). Per iteration:
// issue all 18 A-frag loads -> asm pin (single vmcnt wait) -> 18 MFMA.
// ---------------------------------------------------------------------------
template<int ACT>
__global__ __launch_bounds__(512) void conv_batch(
    const u16* __restrict__ xh, const u16* __restrict__ bond_pad,
    const int* __restrict__ nbr_idx, const u16* __restrict__ wbf_l,
    const float* __restrict__ bfull, const float* __restrict__ sum1,
    const float* __restrict__ sq1, const float* __restrict__ g1,
    const float* __restrict__ be1, float* __restrict__ summed,
    float* __restrict__ o_sum, float* __restrict__ o_sq){
  extern __shared__ char smem[];
  float* gbuf = (float*)smem;                 // ACT: 48*GS f32
  float* pbuf = gbuf + 48 * GS;               // ACT: 4*64 f32
  float* redS = ACT ? (pbuf + 4 * 64) : (float*)smem;
  float* redQ = redS + (ACT ? 64 : 128);

  const int tid = threadIdx.x;
  const int wv = tid >> 6;                    // n-tile 0..7
  const int lane = tid & 63, q = lane >> 4, nloc = lane & 15;

  bf16x8 Bf[6];
  const bf16x8* Bv = (const bf16x8*)wbf_l;
  #pragma unroll
  for (int c = 0; c < 6; c++) Bf[c] = Bv[(c * 8 + wv) * 64 + lane];
  const float bias = bfull[wv * 16 + nloc];

  float A0 = 0.f, B0 = 0.f, A1 = 0.f, B1 = 0.f;
  if (ACT){
    const int cl = tid & 63;
    const float invR = 1.f / (float)(NATOM * MNBR);
    float m0 = sum1[cl] * invR;
    float v0 = fmaxf(sq1[cl] * invR - m0 * m0, 0.f);
    A0 = g1[cl] * rsqrtf(v0 + 1e-5f);  B0 = be1[cl] - m0 * A0;
    float m1 = sum1[64 + cl] * invR;
    float v1 = fmaxf(sq1[64 + cl] * invR - m1 * m1, 0.f);
    A1 = g1[64 + cl] * rsqrtf(v1 + 1e-5f);  B1 = be1[64 + cl] - m1 * A1;
  }
  float sAcc = 0.f, qAcc = 0.f;
  if (tid < (ACT ? 64 : 128)){ redS[tid] = 0.f; redQ[tid] = 0.f; }

  // loop-invariant self-atom sub-offsets
  const int na_off0 = nloc / 12;
  const int na_off1 = (16 + nloc) / 12;
  const int na_off2 = (32 + nloc) / 12;

  const bf16x8* xv = (const bf16x8*)xh;
  const bf16x8 zero8 = {0,0,0,0,0,0,0,0};
  const int s0 = blockIdx.x;

  // indices for the first supertile (prefetched 1 ahead thereafter)
  int nbc0 = nbr_idx[s0 * 48 + nloc];
  int nbc1 = nbr_idx[s0 * 48 + 16 + nloc];
  int nbc2 = nbr_idx[s0 * 48 + 32 + nloc];

  #pragma unroll 1
  for (int k = 0; k < 5; k++){
    const int s = s0 + k * CGRID;
    const size_t e0 = (size_t)s * 48 + nloc;
    // --- issue ALL 18 fragment loads (bond first: HBM latency) ---
    const bf16x8* bp0 = (const bf16x8*)(bond_pad + e0 * 48);
    const bf16x8* bp1 = (const bf16x8*)(bond_pad + (e0 + 16) * 48);
    const bf16x8* bp2 = (const bf16x8*)(bond_pad + (e0 + 32) * 48);
    bf16x8 d00 = bp0[q], d01 = (q < 2) ? bp0[4 + q] : zero8;
    bf16x8 d10 = bp1[q], d11 = (q < 2) ? bp1[4 + q] : zero8;
    bf16x8 d20 = bp2[q], d21 = (q < 2) ? bp2[4 + q] : zero8;
    const int na0 = s * 4 + na_off0, na1 = s * 4 + na_off1, na2 = s * 4 + na_off2;
    bf16x8 x00 = xv[(size_t)na0 * 8 + q],   x01 = xv[(size_t)na0 * 8 + 4 + q];
    bf16x8 x02 = xv[(size_t)nbc0 * 8 + q],  x03 = xv[(size_t)nbc0 * 8 + 4 + q];
    bf16x8 x10 = xv[(size_t)na1 * 8 + q],   x11 = xv[(size_t)na1 * 8 + 4 + q];
    bf16x8 x12 = xv[(size_t)nbc1 * 8 + q],  x13 = xv[(size_t)nbc1 * 8 + 4 + q];
    bf16x8 x20 = xv[(size_t)na2 * 8 + q],   x21 = xv[(size_t)na2 * 8 + 4 + q];
    bf16x8 x22 = xv[(size_t)nbc2 * 8 + q],  x23 = xv[(size_t)nbc2 * 8 + 4 + q];
    // prefetch next supertile's indices (waited next iteration)
    if (k < 4){
      nbc0 = nbr_idx[(s + CGRID) * 48 + nloc];
      nbc1 = nbr_idx[(s + CGRID) * 48 + 16 + nloc];
      nbc2 = nbr_idx[(s + CGRID) * 48 + 32 + nloc];
    }
    // --- pin: all 18 frags must be materialized here (ONE batched wait) ---
    asm volatile("" :
      "+v"(d00), "+v"(d01), "+v"(d10), "+v"(d11), "+v"(d20), "+v"(d21),
      "+v"(x00), "+v"(x01), "+v"(x02), "+v"(x03),
      "+v"(x10), "+v"(x11), "+v"(x12), "+v"(x13),
      "+v"(x20), "+v"(x21), "+v"(x22), "+v"(x23));
    // --- MFMA phase: 3 et-groups x 6 MFMA ---
    #pragma unroll
    for (int et = 0; et < 3; et++){
      bf16x8 b0_ = (et == 0) ? d00 : (et == 1) ? d10 : d20;
      bf16x8 b1_ = (et == 0) ? d01 : (et == 1) ? d11 : d21;
      bf16x8 a0_ = (et == 0) ? x00 : (et == 1) ? x10 : x20;
      bf16x8 a1_ = (et == 0) ? x01 : (et == 1) ? x11 : x21;
      bf16x8 a2_ = (et == 0) ? x02 : (et == 1) ? x12 : x22;
      bf16x8 a3_ = (et == 0) ? x03 : (et == 1) ? x13 : x23;
      f32x4 acc = {bias, bias, bias, bias};
      acc = __builtin_amdgcn_mfma_f32_16x16x32_bf16(b0_, Bf[4], acc, 0, 0, 0);
      acc = __builtin_amdgcn_mfma_f32_16x16x32_bf16(b1_, Bf[5], acc, 0, 0, 0);
      acc = __builtin_amdgcn_mfma_f32_16x16x32_bf16(a0_, Bf[0], acc, 0, 0, 0);
      acc = __builtin_amdgcn_mfma_f32_16x16x32_bf16(a1_, Bf[1], acc, 0, 0, 0);
      acc = __builtin_amdgcn_mfma_f32_16x16x32_bf16(a2_, Bf[2], acc, 0, 0, 0);
      acc = __builtin_amdgcn_mfma_f32_16x16x32_bf16(a3_, Bf[3], acc, 0, 0, 0);
      if (ACT){
        const int col = wv * 16 + nloc;
        const int r0 = et * 16 + q * 4;
        gbuf[(r0 + 0) * GS + col] = acc[0];
        gbuf[(r0 + 1) * GS + col] = acc[1];
        gbuf[(r0 + 2) * GS + col] = acc[2];
        gbuf[(r0 + 3) * GS + col] = acc[3];
      } else {
        sAcc += acc[0] + acc[1] + acc[2] + acc[3];
        qAcc += acc[0]*acc[0] + acc[1]*acc[1] + acc[2]*acc[2] + acc[3]*acc[3];
      }
    }
    if (ACT){
      // barrier 1: gbuf complete (LDS-only drain; keep vm prefetch in flight)
      __builtin_amdgcn_sched_barrier(0);
      asm volatile("s_waitcnt lgkmcnt(0)");
      __builtin_amdgcn_s_barrier();
      __builtin_amdgcn_sched_barrier(0);
      const int cl = tid & 63, a = tid >> 7, h = (tid >> 6) & 1;
      float ph = 0.f;
      #pragma unroll
      for (int m = 0; m < 6; m++){
        int el = a * 12 + h * 6 + m;
        float u = fmaf(gbuf[el * GS + cl],      A0, B0);
        float v = fmaf(gbuf[el * GS + 64 + cl], A1, B1);
        ph = fmaf(sigmoid_fast(u), softplus_fast(v), ph);
      }
      if (h) pbuf[a * 64 + cl] = ph;
      // barrier 2: pbuf ready; also orders gbuf reads before next-iter writes
      __builtin_amdgcn_sched_barrier(0);
      asm volatile("s_waitcnt lgkmcnt(0)");
      __builtin_amdgcn_s_barrier();
      __builtin_amdgcn_sched_barrier(0);
      if (!h){
        float p = ph + pbuf[a * 64 + cl];
        summed[((size_t)s * 4 + a) * 64 + cl] = p;
        sAcc += p;  qAcc = fmaf(p, p, qAcc);
      }
    }
  }

  __syncthreads();
  if (ACT){
    if (!((tid >> 6) & 1)){
      atomicAdd(&redS[tid & 63], sAcc);
      atomicAdd(&redQ[tid & 63], qAcc);
    }
    __syncthreads();
    if (tid < 64){ atomicAdd(&o_sum[tid], redS[tid]); atomicAdd(&o_sq[tid], redQ[tid]); }
  } else {
    int c0 = wv * 16 + nloc;
    atomicAdd(&redS[c0], sAcc);
    atomicAdd(&redQ[c0], qAcc);
    __syncthreads();
    if (tid < 128){ atomicAdd(&o_sum[tid], redS[tid]); atomicAdd(&o_sq[tid], redQ[tid]); }
  }
}

// R7 fallback conv pass (small-ws path; reads raw nbr_fea, no bond_pad).
template<int ACT>
__global__ __launch_bounds__(256, 3) void conv_mfma(
    const u16* __restrict__ xh, const void* __restrict__ nbr_fea,
    const int* __restrict__ nbr_idx, const u16* __restrict__ wbf_l,
    const float* __restrict__ bfull, const float* __restrict__ sum1,
    const float* __restrict__ sq1, const float* __restrict__ g1,
    const float* __restrict__ be1, float* __restrict__ summed,
    float* __restrict__ o_sum, float* __restrict__ o_sq,
    const int* __restrict__ flag){
  extern __shared__ char smem[];
  u16*   fragA = (u16*)smem;                      // 6*512 u16
  float* gbuf  = (float*)(smem + 6144);           // ACT only: 48*GS
  float* redS  = ACT ? (gbuf + 48 * GS) : (float*)(smem + 6144);
  float* redQ  = redS + (ACT ? 64 : 128);

  const int tid = threadIdx.x;
  const int w = tid >> 6, lane = tid & 63;
  const int q = lane >> 4, nloc = lane & 15, q8 = q * 8;
  const int isbf = *flag;

  bf16x8 Bf[6][2];
  const bf16x8* Bv = (const bf16x8*)wbf_l;
  #pragma unroll
  for (int c = 0; c < 6; c++)
    #pragma unroll
    for (int t2 = 0; t2 < 2; t2++)
      Bf[c][t2] = Bv[(c * 8 + w * 2 + t2) * 64 + lane];
  float bias0 = bfull[w * 32 + nloc];
  float bias1 = bfull[w * 32 + 16 + nloc];

  float A0 = 0.f, B0 = 0.f, A1 = 0.f, B1 = 0.f;
  if (ACT){
    const float invR = 1.f / (float)(NATOM * MNBR);
    float m0 = sum1[lane] * invR;
    float v0 = fmaxf(sq1[lane] * invR - m0 * m0, 0.f);
    A0 = g1[lane] * rsqrtf(v0 + 1e-5f);  B0 = be1[lane] - m0 * A0;
    float m1 = sum1[64 + lane] * invR;
    float v1 = fmaxf(sq1[64 + lane] * invR - m1 * m1, 0.f);
    A1 = g1[64 + lane] * rsqrtf(v1 + 1e-5f);  B1 = be1[64 + lane] - m1 * A1;
  }
  float sAcc0 = 0.f, sAcc1 = 0.f, qAcc0 = 0.f, qAcc1 = 0.f;
  if (tid < (ACT ? 64 : 128)){ redS[tid] = 0.f; redQ[tid] = 0.f; }

  const bf16x8* xv = (const bf16x8*)xh;
  for (int s = blockIdx.x; s < NSUP; s += gridDim.x){
    int e0 = s * 48 + nloc;
    int nb0 = nbr_idx[e0], nb1 = nbr_idx[e0 + 16], nb2 = nbr_idx[e0 + 32];
    bf16x8 Af[3][6];
    if (w < 3){
      size_t eg = (size_t)(s * 48 + w * 16 + nloc);
      u16 v4[8], v5[8];
      if (isbf){
        const u16* br = (const u16*)nbr_fea + eg * 41;
        #pragma unroll
        for (int i = 0; i < 8; i++) v4[i] = br[q8 + i];
        #pragma unroll
        for (int i = 0; i < 8; i++){
          int k5 = 32 + q8 + i;
          v5[i] = (k5 < 41) ? br[k5] : (u16)0;
        }
      } else {
        const float* br = (const float*)nbr_fea + eg * 41;
        #pragma unroll
        for (int i = 0; i < 8; i++) v4[i] = f2bf(br[q8 + i]);
        #pragma unroll
        for (int i = 0; i < 8; i++){
          int k5 = 32 + q8 + i;
          v5[i] = (k5 < 41) ? f2bf(br[k5]) : (u16)0;
        }
      }
      *(uint4*)&fragA[(w * 2 + 0) * 512 + lane * 8] = *(uint4*)v4;
      *(uint4*)&fragA[(w * 2 + 1) * 512 + lane * 8] = *(uint4*)v5;
    }
    __syncthreads();
    #pragma unroll
    for (int et = 0; et < 3; et++){
      int nb = (et == 0) ? nb0 : (et == 1) ? nb1 : nb2;
      int na = s * 4 + (et * 16 + nloc) / 12;
      Af[et][0] = xv[na * 8 + q];
      Af[et][1] = xv[na * 8 + 4 + q];
      Af[et][2] = xv[nb * 8 + q];
      Af[et][3] = xv[nb * 8 + 4 + q];
      Af[et][4] = *(bf16x8*)&fragA[(et * 2 + 0) * 512 + lane * 8];
      Af[et][5] = *(bf16x8*)&fragA[(et * 2 + 1) * 512 + lane * 8];
    }
    #pragma unroll
    for (int et = 0; et < 3; et++){
      #pragma unroll
      for (int t2 = 0; t2 < 2; t2++){
        float bs = t2 ? bias1 : bias0;
        f32x4 acc = {bs, bs, bs, bs};
        acc = __builtin_amdgcn_mfma_f32_16x16x32_bf16(Af[et][0], Bf[0][t2], acc, 0, 0, 0);
        acc = __builtin_amdgcn_mfma_f32_16x16x32_bf16(Af[et][1], Bf[1][t2], acc, 0, 0, 0);
        acc = __builtin_amdgcn_mfma_f32_16x16x32_bf16(Af[et][2], Bf[2][t2], acc, 0, 0, 0);
        acc = __builtin_amdgcn_mfma_f32_16x16x32_bf16(Af[et][3], Bf[3][t2], acc, 0, 0, 0);
        acc = __builtin_amdgcn_mfma_f32_16x16x32_bf16(Af[et][4], Bf[4][t2], acc, 0, 0, 0);
        acc = __builtin_amdgcn_mfma_f32_16x16x32_bf16(Af[et][5], Bf[5][t2], acc, 0, 0, 0);
        if (ACT){
          int col = w * 32 + t2 * 16 + nloc;
          int r0 = et * 16 + q * 4;
          gbuf[(r0 + 0) * GS + col] = acc[0];
          gbuf[(r0 + 1) * GS + col] = acc[1];
          gbuf[(r0 + 2) * GS + col] = acc[2];
          gbuf[(r0 + 3) * GS + col] = acc[3];
        } else {
          float ss = acc[0] + acc[1] + acc[2] + acc[3];
          float qq = acc[0]*acc[0] + acc[1]*acc[1] + acc[2]*acc[2] + acc[3]*acc[3];
          if (t2){ sAcc1 += ss; qAcc1 += qq; } else { sAcc0 += ss; qAcc0 += qq; }
        }
      }
    }
    if (ACT){
      __syncthreads();
      float p = 0.f;
      #pragma unroll
      for (int m = 0; m < 12; m++){
        int el = w * 12 + m;
        float u = fmaf(gbuf[el * GS + lane],      A0, B0);
        float v = fmaf(gbuf[el * GS + 64 + lane], A1, B1);
        p = fmaf(sigmoid_fast(u), softplus_fast(v), p);
      }
      summed[(s * 4 + w) * 64 + lane] = p;
      sAcc0 += p;  qAcc0 = fmaf(p, p, qAcc0);
    }
    __syncthreads();
  }
  if (ACT){
    atomicAdd(&redS[lane], sAcc0);
    atomicAdd(&redQ[lane], qAcc0);
    __syncthreads();
    if (tid < 64){ atomicAdd(&o_sum[tid], redS[tid]); atomicAdd(&o_sq[tid], redQ[tid]); }
  } else {
    int c0 = w * 32 + nloc;
    atomicAdd(&redS[c0], sAcc0);       atomicAdd(&redQ[c0], qAcc0);
    atomicAdd(&redS[c0 + 16], sAcc1);  atomicAdd(&redQ[c0 + 16], qAcc1);
    __syncthreads();
    if (tid < 128){ atomicAdd(&o_sum[tid], redS[tid]); atomicAdd(&o_sq[tid], redQ[tid]); }
  }
}

__global__ __launch_bounds__(256) void update_x_kernel(
    float* __restrict__ x, u16* __restrict__ xh,
    const float* __restrict__ summed,
    const float* __restrict__ sum2, const float* __restrict__ sq2,
    const float* __restrict__ g2, const float* __restrict__ be2){
  int idx = blockIdx.x * 256 + threadIdx.x;
  int f = idx & 63;
  const float invN = 1.f / (float)NATOM;
  float mean = sum2[f] * invN;
  float var  = fmaxf(sq2[f] * invN - mean * mean, 0.f);
  float a = g2[f] * rsqrtf(var + 1e-5f);
  float b = be2[f] - mean * a;
  float v = x[idx] + fmaf(summed[idx], a, b);
  float r = softplusf_(v);
  x[idx] = r;
  xh[idx] = f2bf(r);
}

__global__ __launch_bounds__(256) void pool_kernel(
    const float* __restrict__ x, const int* __restrict__ cidx,
    float* __restrict__ crys, float* __restrict__ cnt){
  int idx = blockIdx.x * 256 + threadIdx.x;
  int n = idx >> 6, f = idx & 63;
  int c = cidx[n];
  atomicAdd(&crys[c * FD + f], x[idx]);
  if (f == 0) atomicAdd(&cnt[c], 1.f);
}

__global__ __launch_bounds__(128) void head_kernel(
    const float* __restrict__ crys, const float* __restrict__ cnt,
    const float* __restrict__ W_fc, const float* __restrict__ b_fc,
    const float* __restrict__ W_out, const float* __restrict__ b_out,
    void* __restrict__ out, const int* __restrict__ flag){
  __shared__ float p_s[FD];
  __shared__ float red_s[HD];
  int c = blockIdx.x, tid = threadIdx.x;
  if (tid < FD){
    float ct = fmaxf(cnt[c], 1.f);
    p_s[tid] = softplusf_(crys[c * FD + tid] / ct);
  }
  __syncthreads();
  float acc = b_fc[tid];
  for (int k = 0; k < FD; k++)
    acc = fmaf(p_s[k], W_fc[k * HD + tid], acc);
  float h = softplusf_(acc);
  red_s[tid] = h * W_out[tid];
  __syncthreads();
  for (int s = HD / 2; s > 0; s >>= 1){
    if (tid < s) red_s[tid] += red_s[tid + s];
    __syncthreads();
  }
  if (tid == 0){
    float r = red_s[0] + b_out[0];
    if (*flag) ((u16*)out)[c] = f2bf(r);
    else       ((float*)out)[c] = r;
  }
}

extern "C" void kernel_launch(void* const* d_in, const int* in_sizes, int n_in,
                              void* d_out, int out_size, void* d_ws, size_t ws_size,
                              hipStream_t stream){
  if (ws_size < WS_NEED_BYTES) return;  // diagnostic: leaves d_out zeroed
  const bool full = (ws_size >= WS_FULL_BYTES);
  const void* atom_fea = d_in[0];
  const void* nbr_fea  = d_in[1];
  const int* nbr_idx   = (const int*)d_in[2];
  const int* cidx      = (const int*)d_in[3];

  float* ws     = (float*)d_ws;
  float* x      = ws + OFF_X;
  u16*   xh     = (u16*)(ws + OFF_XH);
  float* summed = ws + OFF_SUMMED;
  float* sum1   = ws + OFF_STATS;
  float* sq1    = sum1 + 128;
  float* sum2   = sq1 + 128;
  float* sq2    = sum2 + 64;
  float* crys   = ws + OFF_CRYS;
  float* cnt    = ws + OFF_CNT;
  float* wc     = ws + OFF_WCONV;
  u16*   wbf    = (u16*)(ws + OFF_WBF);
  int*   flag   = (int*)(ws + OFF_FLAG);
  u16*   bpad   = (u16*)(ws + OFF_BPAD);

  detect_kernel<<<1, 64, 0, stream>>>((const u16*)nbr_fea, flag);
  CvtArgs ca;
  const int srcidx[12] = {4,5,6,7,8,9,10,11,12,13,14,15};
  const int starts[13] = {W_EMB_O, B_EMB_O, W_FULL_O, B_FULL_O, G1_O, BE1_O,
                          G2_O, BE2_O, W_FC_O, B_FC_O, W_OUT_O, B_OUT_O, WC_TOTAL};
  for (int i = 0; i < 12; i++){ ca.src[i] = d_in[srcidx[i]]; ca.start[i] = starts[i]; }
  ca.start[12] = WC_TOTAL;
  cvt_all_kernel<<<(WC_TOTAL + 255) / 256, 256, 0, stream>>>(ca, wc, flag);
  build_bfrag<<<(9216 + 255) / 256, 256, 0, stream>>>(wc + W_FULL_O, wbf);
  if (full) bond_prep<<<NSUP, 256, 0, stream>>>(nbr_fea, bpad, flag);

  embed_kernel<<<NATOM / 4, 256, 0, stream>>>(atom_fea, wc + W_EMB_O, wc + B_EMB_O,
                                              x, xh, flag);
  const int LDS_STATS_B = 2 * 128 * 4;                          // 1024
  const int LDS_ACT_B   = (48 * GS + 4 * 64 + 2 * 64) * 4;      // 26880
  const int LDS_STATS_F = 6144 + 2 * 128 * 4;                   // 7168
  const int LDS_ACT_F   = 6144 + (48 * GS + 128) * 4;           // 32000
  for (int i = 0; i < 3; i++){
    const u16* wbf_l = wbf + (size_t)i * 3072 * 8;
    hipMemsetAsync(sum1, 0, 384 * sizeof(float), stream);
    if (full){
      conv_batch<0><<<CGRID, 512, LDS_STATS_B, stream>>>(xh, bpad, nbr_idx,
          wbf_l, wc + B_FULL_O + i * F2D, sum1, sq1, wc + G1_O + i * F2D,
          wc + BE1_O + i * F2D, summed, sum1, sq1);
      conv_batch<1><<<CGRID, 512, LDS_ACT_B, stream>>>(xh, bpad, nbr_idx,
          wbf_l, wc + B_FULL_O + i * F2D, sum1, sq1, wc + G1_O + i * F2D,
          wc + BE1_O + i * F2D, summed, sum2, sq2);
    } else {
      conv_mfma<0><<<CGRID, 256, LDS_STATS_F, stream>>>(xh, nbr_fea, nbr_idx,
          wbf_l, wc + B_FULL_O + i * F2D, sum1, sq1, wc + G1_O + i * F2D,
          wc + BE1_O + i * F2D, summed, sum1, sq1, flag);
      conv_mfma<1><<<CGRID, 256, LDS_ACT_F, stream>>>(xh, nbr_fea, nbr_idx,
          wbf_l, wc + B_FULL_O + i * F2D, sum1, sq1, wc + G1_O + i * F2D,
          wc + BE1_O + i * F2D, summed, sum2, sq2, flag);
    }
    update_x_kernel<<<(NATOM * FD) / 256, 256, 0, stream>>>(x, xh, summed, sum2, sq2,
        wc + G2_O + i * FD, wc + BE2_O + i * FD);
  }
  hipMemsetAsync(crys, 0, (NCRY * FD + NCRY) * sizeof(float), stream);
  pool_kernel<<<(NATOM * FD) / 256, 256, 0, stream>>>(x, cidx, crys, cnt);
  head_kernel<<<NCRY, 128, 0, stream>>>(crys, cnt, wc + W_FC_O, wc + B_FC_O,
      wc + W_OUT_O, wc + B_OUT_O, d_out, flag);
}

// Round 8
// 998.611 us; speedup vs baseline: 1.4869x; 1.4869x over previous
//
#include <hip/hip_runtime.h>
#include <hip/hip_bf16.h>

// CGCNN forward, MFMA conv GEMM (R16).
//   g[e,:] = [x[n(e)] | x[nb(e)] | bond(e)] @ Wf + b  (K=169 pad 192, N=128)
// R16 vs R9-R15: every cross-phase prefetch (reg dbuf/DMA/unroll/hoist/
// asm-pin) was defeated by the allocator (spill or forced-serial). R16 uses
// the one structure never tried and proven by the m97 GEMM ladder: a plain
// single-buffer 2-barrier loop with A-fragments SHARED across waves via LDS:
//   - stage: 256 threads load 704 16B chunks (bond frag-major + 4 self rows
//     + 48 nbr rows frag-major) -> ds_write IMMEDIATELY (transient regs, no
//     state held across MFMA -> no spill incentive).
//   - __syncthreads -> all 4 waves read shared frags (R10-verified layout &
//     addressing) -> 36 MFMA -> barrier.
//   - kills the 4x redundant gather (184->46MB L3 traffic/dispatch) and
//     collapses the per-supertile chain to ONE gather latency; phase overlap
//     comes from 3-4 resident blocks/CU (m97 mechanism), not from ILP the
//     compiler won't give.
// Stage formulas = R11's (verified); LDS layout + reads = R10's (verified);
// bond_prep = R10 fragment-major (verified). Canary: WRITE 16.5MB(ACT)/
// ~1MB(stats), VGPR 80-100.
// R7 LDS-staging fallback kept for ws_size < 108.5 MB.

#define NATOM 60000
#define MNBR  12
#define F0D   92
#define FBD   41
#define FD    64
#define F2D   128
#define NCRY  2000
#define HD    128
#define NSUP  15000          // 720000 edges / 48
#define GS    132            // gbuf row stride (floats)

// ws layout (float units)
#define OFF_X      0ull          // 3,840,000 f32
#define OFF_XH     3840000ull    // 3,840,000 u16
#define OFF_SUMMED 5760000ull    // 3,840,000 f32
#define OFF_STATS  9600000ull    // sum1[128] sq1[128] sum2[64] sq2[64]
#define OFF_CRYS   9600384ull
#define OFF_CNT    9728384ull
#define OFF_WCONV  9730384ull    // 80,833 f32
#define OFF_WBF    9811220ull    // 73,728 u16 = 36,864 f slots
#define OFF_FLAG   9848084ull
#define WS_NEED_BYTES (9848085ull * 4ull)
#define OFF_BPAD   9848088ull    // 34,560,000 u16 = 17,280,000 f slots (16B aligned)
#define WS_FULL_BYTES ((OFF_BPAD + 17280000ull) * 4ull)   // 108,512,352

// offsets inside wconv
#define W_EMB_O  0
#define B_EMB_O  5888
#define W_FULL_O 5952
#define B_FULL_O 70848
#define G1_O     71232
#define BE1_O    71616
#define G2_O     72000
#define BE2_O    72192
#define W_FC_O   72384
#define B_FC_O   80576
#define W_OUT_O  80704
#define B_OUT_O  80832
#define WC_TOTAL 80833

typedef unsigned short u16;
typedef __attribute__((ext_vector_type(8))) short bf16x8;
typedef __attribute__((ext_vector_type(4))) float f32x4;

__device__ __forceinline__ float bf2f(u16 u){
  union { unsigned int i; float f; } v; v.i = ((unsigned int)u) << 16; return v.f;
}
__device__ __forceinline__ u16 f2bf(float f){
  union { float f; unsigned int i; } v; v.f = f;
  unsigned int x = v.i;
  return (u16)((x + 0x7FFFu + ((x >> 16) & 1u)) >> 16);
}
__device__ __forceinline__ float softplusf_(float x){
  return fmaxf(x, 0.f) + log1pf(expf(-fabsf(x)));
}
__device__ __forceinline__ float softplus_fast(float x){
  return fmaxf(x, 0.f) + __logf(1.f + __expf(-fabsf(x)));
}
__device__ __forceinline__ float sigmoid_fast(float x){
  return __builtin_amdgcn_rcpf(1.f + __expf(-x));
}

__global__ __launch_bounds__(64) void detect_kernel(
    const u16* __restrict__ data, int* __restrict__ flag){
  int tid = threadIdx.x;
  float v = bf2f(data[tid * 2]);
  float av = fabsf(v);
  bool sane = (av > 1e-6f) && (av < 100.f);
  unsigned long long m = __ballot(sane);
  if (tid == 0) *flag = (__popcll(m) >= 32) ? 1 : 0;
}

struct CvtArgs {
  const void* src[12];
  int start[13];
};

__global__ __launch_bounds__(256) void cvt_all_kernel(
    CvtArgs a, float* __restrict__ dst, const int* __restrict__ flag){
  int i = blockIdx.x * 256 + threadIdx.x;
  if (i >= WC_TOTAL) return;
  int r = 0;
  while (i >= a.start[r + 1]) r++;
  int rel = i - a.start[r];
  if (*flag) dst[i] = bf2f(((const u16*)a.src[r])[rel]);
  else       dst[i] = ((const float*)a.src[r])[rel];
}

__global__ __launch_bounds__(256) void build_bfrag(
    const float* __restrict__ wfull, u16* __restrict__ wbf){
  int t = blockIdx.x * 256 + threadIdx.x;
  if (t >= 3 * 6 * 8 * 64) return;
  int lane = t & 63, nt = (t >> 6) & 7, c = (t >> 9) % 6, layer = t / 3072;
  int q = lane >> 4, nloc = lane & 15;
  u16 vals[8];
  #pragma unroll
  for (int i = 0; i < 8; i++){
    int k = c * 32 + q * 8 + i;
    float v = (k < 169) ? wfull[layer * 169 * F2D + k * F2D + nt * 16 + nloc] : 0.f;
    vals[i] = f2bf(v);
  }
  *(uint4*)&wbf[(size_t)t * 8] = *(uint4*)vals;
}

// One-time repack, FRAGMENT-MAJOR per supertile (288 16B slots, R10-verified):
//   slot j: et=j/96, jj=j%96
//     jj<64 : chunk4 — lane=jj, row=et*16+(lane&15), feats (lane>>4)*8..+7
//     jj>=64: chunk5 — l2=jj-64, row=et*16+(l2&15), feats 32+(l2>>4)*8..+7
__global__ __launch_bounds__(256) void bond_prep(
    const void* __restrict__ nbr_fea, u16* __restrict__ bond_pad,
    const int* __restrict__ flag){
  __shared__ __align__(16) char sm[7872];
  u16*   lb_u = (u16*)sm;
  float* lb_f = (float*)sm;
  int s = blockIdx.x, tid = threadIdx.x;
  const int isbf = *flag;
  if (isbf){
    const uint4* src = (const uint4*)((const u16*)nbr_fea + (size_t)s * 1968);
    if (tid < 246) ((uint4*)sm)[tid] = src[tid];
  } else {
    const uint4* src = (const uint4*)((const float*)nbr_fea + (size_t)s * 1968);
    for (int t = tid; t < 492; t += 256) ((uint4*)sm)[t] = src[t];
  }
  __syncthreads();
  uint4* outv = (uint4*)(bond_pad + (size_t)s * 2304);
  for (int slot = tid; slot < 288; slot += 256){
    int et = slot / 96, jj = slot - et * 96;
    int l  = (jj < 64) ? jj : (jj - 64);
    int row = et * 16 + (l & 15);
    int kb  = ((jj < 64) ? 0 : 32) + (l >> 4) * 8;
    u16 v[8];
    #pragma unroll
    for (int i = 0; i < 8; i++){
      int k = kb + i;
      v[i] = (k < FBD) ? (isbf ? lb_u[row * FBD + k] : f2bf(lb_f[row * FBD + k])) : (u16)0;
    }
    outv[slot] = *(uint4*)v;
  }
}

__global__ __launch_bounds__(256) void embed_kernel(
    const void* __restrict__ atom_fea, const float* __restrict__ W_emb,
    const float* __restrict__ b_emb, float* __restrict__ x,
    u16* __restrict__ xh, const int* __restrict__ flag){
  int tid = threadIdx.x;
  int n = blockIdx.x * 4 + (tid >> 6);
  int f = tid & 63;
  float acc = b_emb[f];
  if (*flag){
    const u16* arow = (const u16*)atom_fea + n * F0D;
    for (int k = 0; k < F0D; k++)
      acc = fmaf(bf2f(arow[k]), W_emb[k * FD + f], acc);
  } else {
    const float* arow = (const float*)atom_fea + n * F0D;
    for (int k = 0; k < F0D; k++)
      acc = fmaf(arow[k], W_emb[k * FD + f], acc);
  }
  x[n * FD + f] = acc;
  xh[n * FD + f] = f2bf(acc);
}

// ---------------------------------------------------------------------------
// R16: single-buffer shared-A conv pass. LDS stage buffer (11264 B, R10
// layout): [0,4608) bond frag-major; [4608,5120) self 4x128B; [5120,11264)
// nbr frag-major (chunk m: row (m>>7)*16+(m&15), bytes (((m>>6)&1)*4+
// ((m>>4)&3))*16). 704 chunks staged by 256 thr in 3 rounds.
// ---------------------------------------------------------------------------
template<int ACT>
__global__ __launch_bounds__(256, 3) void conv_share(
    const u16* __restrict__ xh, const u16* __restrict__ bond_pad,
    const int* __restrict__ nbr_idx, const u16* __restrict__ wbf_l,
    const float* __restrict__ bfull, const float* __restrict__ sum1,
    const float* __restrict__ sq1, const float* __restrict__ g1,
    const float* __restrict__ be1, float* __restrict__ summed,
    float* __restrict__ o_sum, float* __restrict__ o_sq){
  extern __shared__ char smem[];
  char* stg  = smem;                                  // 11264 B
  float* gbuf = (float*)(smem + 11264);               // ACT only: 48*GS
  float* redS = ACT ? (gbuf + 48 * GS) : (float*)(smem + 11264);
  float* redQ = redS + (ACT ? 64 : 128);

  const int tid = threadIdx.x;
  const int w = tid >> 6, lane = tid & 63;
  const int q = lane >> 4, nloc = lane & 15;

  bf16x8 Bf[6][2];
  const bf16x8* Bv = (const bf16x8*)wbf_l;
  #pragma unroll
  for (int c = 0; c < 6; c++)
    #pragma unroll
    for (int t2 = 0; t2 < 2; t2++)
      Bf[c][t2] = Bv[(c * 8 + w * 2 + t2) * 64 + lane];
  float bias0 = bfull[w * 32 + nloc];
  float bias1 = bfull[w * 32 + 16 + nloc];

  float A0 = 0.f, B0 = 0.f, A1 = 0.f, B1 = 0.f;
  if (ACT){
    const float invR = 1.f / (float)(NATOM * MNBR);
    float m0 = sum1[lane] * invR;
    float v0 = fmaxf(sq1[lane] * invR - m0 * m0, 0.f);
    A0 = g1[lane] * rsqrtf(v0 + 1e-5f);  B0 = be1[lane] - m0 * A0;
    float m1 = sum1[64 + lane] * invR;
    float v1 = fmaxf(sq1[64 + lane] * invR - m1 * m1, 0.f);
    A1 = g1[64 + lane] * rsqrtf(v1 + 1e-5f);  B1 = be1[64 + lane] - m1 * A1;
  }
  float sAcc0 = 0.f, sAcc1 = 0.f, qAcc0 = 0.f, qAcc1 = 0.f;
  if (tid < (ACT ? 64 : 128)){ redS[tid] = 0.f; redQ[tid] = 0.f; }

  // per-thread staging parameters (R11-verified formulas)
  const char* xh8   = (const char*)xh;
  const char* bpad8 = (const char*)bond_pad;
  const int jx1 = tid - 64;                    // round-1 nbr chunks [0,192)
  const int rA  = (tid >= 64) ? ((jx1 >> 7) * 16 + (jx1 & 15)) : 0;
  const int cg1 = (tid >= 64) ? ((((jx1 >> 6) & 1) * 4 + ((jx1 >> 4) & 3)) * 16) : 0;
  const int jx2 = tid + 192;                   // round-2 nbr chunks [192,384)
  const int rB  = (tid < 192) ? ((jx2 >> 7) * 16 + (jx2 & 15)) : 0;
  const int cg2 = (tid < 192) ? ((((jx2 >> 6) & 1) * 4 + ((jx2 >> 4) & 3)) * 16) : 0;

  // loop-invariant self-atom sub-offsets for the consume phase
  const int na_off0 = nloc / 12;
  const int na_off1 = (16 + nloc) / 12;
  const int na_off2 = (32 + nloc) / 12;

  const bf16x8 zero8 = {0,0,0,0,0,0,0,0};

  for (int s = blockIdx.x; s < NSUP; s += gridDim.x){
    // ---- stage: load -> ds_write immediately (transient regs) ----
    {
      int nbA = nbr_idx[s * 48 + rA];
      int nbB = nbr_idx[s * 48 + rB];
      uint4 rb = *(const uint4*)(bpad8 + (size_t)s * 4608 + (size_t)tid * 16);
      const char* p1;
      if (tid < 32)      p1 = bpad8 + (size_t)s * 4608 + (size_t)(tid + 256) * 16;
      else if (tid < 64) p1 = xh8 + (size_t)s * 512 + (size_t)(tid - 32) * 16;
      else               p1 = xh8 + (size_t)nbA * 128 + cg1;
      uint4 r1 = *(const uint4*)p1;
      *(uint4*)(stg + tid * 16) = rb;
      *(uint4*)(stg + 4096 + tid * 16) = r1;
      if (tid < 192){
        uint4 r2 = *(const uint4*)(xh8 + (size_t)nbB * 128 + cg2);
        *(uint4*)(stg + 8192 + tid * 16) = r2;
      }
    }
    __syncthreads();   // stage buffer complete

    // ---- consume: 3 et-groups, frags from shared LDS (R10 addressing) ----
    #pragma unroll
    for (int et = 0; et < 3; et++){
      int naloc = (et == 0) ? na_off0 : (et == 1) ? na_off1 : na_off2;
      const char* xs = stg + 4608 + naloc * 128;
      bf16x8 a0 = *(const bf16x8*)(xs + q * 16);
      bf16x8 a1 = *(const bf16x8*)(xs + 64 + q * 16);
      bf16x8 a2 = *(const bf16x8*)(stg + 5120 + (et * 128 + lane) * 16);
      bf16x8 a3 = *(const bf16x8*)(stg + 5120 + (et * 128 + 64 + lane) * 16);
      bf16x8 a4 = *(const bf16x8*)(stg + (et * 96 + lane) * 16);
      bf16x8 a5 = (lane < 32) ? *(const bf16x8*)(stg + (et * 96 + 64 + lane) * 16)
                              : zero8;
      #pragma unroll
      for (int t2 = 0; t2 < 2; t2++){
        float bs = t2 ? bias1 : bias0;
        f32x4 acc = {bs, bs, bs, bs};
        acc = __builtin_amdgcn_mfma_f32_16x16x32_bf16(a0, Bf[0][t2], acc, 0, 0, 0);
        acc = __builtin_amdgcn_mfma_f32_16x16x32_bf16(a1, Bf[1][t2], acc, 0, 0, 0);
        acc = __builtin_amdgcn_mfma_f32_16x16x32_bf16(a2, Bf[2][t2], acc, 0, 0, 0);
        acc = __builtin_amdgcn_mfma_f32_16x16x32_bf16(a3, Bf[3][t2], acc, 0, 0, 0);
        acc = __builtin_amdgcn_mfma_f32_16x16x32_bf16(a4, Bf[4][t2], acc, 0, 0, 0);
        acc = __builtin_amdgcn_mfma_f32_16x16x32_bf16(a5, Bf[5][t2], acc, 0, 0, 0);
        if (ACT){
          int col = w * 32 + t2 * 16 + nloc;
          int r0 = et * 16 + q * 4;
          gbuf[(r0 + 0) * GS + col] = acc[0];
          gbuf[(r0 + 1) * GS + col] = acc[1];
          gbuf[(r0 + 2) * GS + col] = acc[2];
          gbuf[(r0 + 3) * GS + col] = acc[3];
        } else {
          float ss = acc[0] + acc[1] + acc[2] + acc[3];
          float qq = acc[0]*acc[0] + acc[1]*acc[1] + acc[2]*acc[2] + acc[3]*acc[3];
          if (t2){ sAcc1 += ss; qAcc1 += qq; } else { sAcc0 += ss; qAcc0 += qq; }
        }
      }
    }
    if (ACT){
      __syncthreads();   // gbuf complete (stage reads also done)
      float p = 0.f;
      #pragma unroll
      for (int m = 0; m < 12; m++){
        int el = w * 12 + m;
        float u = fmaf(gbuf[el * GS + lane],      A0, B0);
        float v = fmaf(gbuf[el * GS + 64 + lane], A1, B1);
        p = fmaf(sigmoid_fast(u), softplus_fast(v), p);
      }
      summed[((size_t)s * 4 + w) * 64 + lane] = p;
      sAcc0 += p;  qAcc0 = fmaf(p, p, qAcc0);
    }
    __syncthreads();   // stage (+gbuf) free for next supertile
  }

  if (ACT){
    atomicAdd(&redS[lane], sAcc0);
    atomicAdd(&redQ[lane], qAcc0);
    __syncthreads();
    if (tid < 64){ atomicAdd(&o_sum[tid], redS[tid]); atomicAdd(&o_sq[tid], redQ[tid]); }
  } else {
    int c0 = w * 32 + nloc;
    atomicAdd(&redS[c0], sAcc0);       atomicAdd(&redQ[c0], qAcc0);
    atomicAdd(&redS[c0 + 16], sAcc1);  atomicAdd(&redQ[c0 + 16], qAcc1);
    __syncthreads();
    if (tid < 128){ atomicAdd(&o_sum[tid], redS[tid]); atomicAdd(&o_sq[tid], redQ[tid]); }
  }
}

// R7 fallback conv pass (small-ws path; reads raw nbr_fea, no bond_pad).
template<int ACT>
__global__ __launch_bounds__(256, 3) void conv_mfma(
    const u16* __restrict__ xh, const void* __restrict__ nbr_fea,
    const int* __restrict__ nbr_idx, const u16* __restrict__ wbf_l,
    const float* __restrict__ bfull, const float* __restrict__ sum1,
    const float* __restrict__ sq1, const float* __restrict__ g1,
    const float* __restrict__ be1, float* __restrict__ summed,
    float* __restrict__ o_sum, float* __restrict__ o_sq,
    const int* __restrict__ flag){
  extern __shared__ char smem[];
  u16*   fragA = (u16*)smem;                      // 6*512 u16
  float* gbuf  = (float*)(smem + 6144);           // ACT only: 48*GS
  float* redS  = ACT ? (gbuf + 48 * GS) : (float*)(smem + 6144);
  float* redQ  = redS + (ACT ? 64 : 128);

  const int tid = threadIdx.x;
  const int w = tid >> 6, lane = tid & 63;
  const int q = lane >> 4, nloc = lane & 15, q8 = q * 8;
  const int isbf = *flag;

  bf16x8 Bf[6][2];
  const bf16x8* Bv = (const bf16x8*)wbf_l;
  #pragma unroll
  for (int c = 0; c < 6; c++)
    #pragma unroll
    for (int t2 = 0; t2 < 2; t2++)
      Bf[c][t2] = Bv[(c * 8 + w * 2 + t2) * 64 + lane];
  float bias0 = bfull[w * 32 + nloc];
  float bias1 = bfull[w * 32 + 16 + nloc];

  float A0 = 0.f, B0 = 0.f, A1 = 0.f, B1 = 0.f;
  if (ACT){
    const float invR = 1.f / (float)(NATOM * MNBR);
    float m0 = sum1[lane] * invR;
    float v0 = fmaxf(sq1[lane] * invR - m0 * m0, 0.f);
    A0 = g1[lane] * rsqrtf(v0 + 1e-5f);  B0 = be1[lane] - m0 * A0;
    float m1 = sum1[64 + lane] * invR;
    float v1 = fmaxf(sq1[64 + lane] * invR - m1 * m1, 0.f);
    A1 = g1[64 + lane] * rsqrtf(v1 + 1e-5f);  B1 = be1[64 + lane] - m1 * A1;
  }
  float sAcc0 = 0.f, sAcc1 = 0.f, qAcc0 = 0.f, qAcc1 = 0.f;
  if (tid < (ACT ? 64 : 128)){ redS[tid] = 0.f; redQ[tid] = 0.f; }

  const bf16x8* xv = (const bf16x8*)xh;
  for (int s = blockIdx.x; s < NSUP; s += gridDim.x){
    int e0 = s * 48 + nloc;
    int nb0 = nbr_idx[e0], nb1 = nbr_idx[e0 + 16], nb2 = nbr_idx[e0 + 32];
    bf16x8 Af[3][6];
    if (w < 3){
      size_t eg = (size_t)(s * 48 + w * 16 + nloc);
      u16 v4[8], v5[8];
      if (isbf){
        const u16* br = (const u16*)nbr_fea + eg * 41;
        #pragma unroll
        for (int i = 0; i < 8; i++) v4[i] = br[q8 + i];
        #pragma unroll
        for (int i = 0; i < 8; i++){
          int k5 = 32 + q8 + i;
          v5[i] = (k5 < 41) ? br[k5] : (u16)0;
        }
      } else {
        const float* br = (const float*)nbr_fea + eg * 41;
        #pragma unroll
        for (int i = 0; i < 8; i++) v4[i] = f2bf(br[q8 + i]);
        #pragma unroll
        for (int i = 0; i < 8; i++){
          int k5 = 32 + q8 + i;
          v5[i] = (k5 < 41) ? f2bf(br[k5]) : (u16)0;
        }
      }
      *(uint4*)&fragA[(w * 2 + 0) * 512 + lane * 8] = *(uint4*)v4;
      *(uint4*)&fragA[(w * 2 + 1) * 512 + lane * 8] = *(uint4*)v5;
    }
    __syncthreads();
    #pragma unroll
    for (int et = 0; et < 3; et++){
      int nb = (et == 0) ? nb0 : (et == 1) ? nb1 : nb2;
      int na = s * 4 + (et * 16 + nloc) / 12;
      Af[et][0] = xv[na * 8 + q];
      Af[et][1] = xv[na * 8 + 4 + q];
      Af[et][2] = xv[nb * 8 + q];
      Af[et][3] = xv[nb * 8 + 4 + q];
      Af[et][4] = *(bf16x8*)&fragA[(et * 2 + 0) * 512 + lane * 8];
      Af[et][5] = *(bf16x8*)&fragA[(et * 2 + 1) * 512 + lane * 8];
    }
    #pragma unroll
    for (int et = 0; et < 3; et++){
      #pragma unroll
      for (int t2 = 0; t2 < 2; t2++){
        float bs = t2 ? bias1 : bias0;
        f32x4 acc = {bs, bs, bs, bs};
        acc = __builtin_amdgcn_mfma_f32_16x16x32_bf16(Af[et][0], Bf[0][t2], acc, 0, 0, 0);
        acc = __builtin_amdgcn_mfma_f32_16x16x32_bf16(Af[et][1], Bf[1][t2], acc, 0, 0, 0);
        acc = __builtin_amdgcn_mfma_f32_16x16x32_bf16(Af[et][2], Bf[2][t2], acc, 0, 0, 0);
        acc = __builtin_amdgcn_mfma_f32_16x16x32_bf16(Af[et][3], Bf[3][t2], acc, 0, 0, 0);
        acc = __builtin_amdgcn_mfma_f32_16x16x32_bf16(Af[et][4], Bf[4][t2], acc, 0, 0, 0);
        acc = __builtin_amdgcn_mfma_f32_16x16x32_bf16(Af[et][5], Bf[5][t2], acc, 0, 0, 0);
        if (ACT){
          int col = w * 32 + t2 * 16 + nloc;
          int r0 = et * 16 + q * 4;
          gbuf[(r0 + 0) * GS + col] = acc[0];
          gbuf[(r0 + 1) * GS + col] = acc[1];
          gbuf[(r0 + 2) * GS + col] = acc[2];
          gbuf[(r0 + 3) * GS + col] = acc[3];
        } else {
          float ss = acc[0] + acc[1] + acc[2] + acc[3];
          float qq = acc[0]*acc[0] + acc[1]*acc[1] + acc[2]*acc[2] + acc[3]*acc[3];
          if (t2){ sAcc1 += ss; qAcc1 += qq; } else { sAcc0 += ss; qAcc0 += qq; }
        }
      }
    }
    if (ACT){
      __syncthreads();
      float p = 0.f;
      #pragma unroll
      for (int m = 0; m < 12; m++){
        int el = w * 12 + m;
        float u = fmaf(gbuf[el * GS + lane],      A0, B0);
        float v = fmaf(gbuf[el * GS + 64 + lane], A1, B1);
        p = fmaf(sigmoid_fast(u), softplus_fast(v), p);
      }
      summed[(s * 4 + w) * 64 + lane] = p;
      sAcc0 += p;  qAcc0 = fmaf(p, p, qAcc0);
    }
    __syncthreads();
  }
  if (ACT){
    atomicAdd(&redS[lane], sAcc0);
    atomicAdd(&redQ[lane], qAcc0);
    __syncthreads();
    if (tid < 64){ atomicAdd(&o_sum[tid], redS[tid]); atomicAdd(&o_sq[tid], redQ[tid]); }
  } else {
    int c0 = w * 32 + nloc;
    atomicAdd(&redS[c0], sAcc0);       atomicAdd(&redQ[c0], qAcc0);
    atomicAdd(&redS[c0 + 16], sAcc1);  atomicAdd(&redQ[c0 + 16], qAcc1);
    __syncthreads();
    if (tid < 128){ atomicAdd(&o_sum[tid], redS[tid]); atomicAdd(&o_sq[tid], redQ[tid]); }
  }
}

__global__ __launch_bounds__(256) void update_x_kernel(
    float* __restrict__ x, u16* __restrict__ xh,
    const float* __restrict__ summed,
    const float* __restrict__ sum2, const float* __restrict__ sq2,
    const float* __restrict__ g2, const float* __restrict__ be2){
  int idx = blockIdx.x * 256 + threadIdx.x;
  int f = idx & 63;
  const float invN = 1.f / (float)NATOM;
  float mean = sum2[f] * invN;
  float var  = fmaxf(sq2[f] * invN - mean * mean, 0.f);
  float a = g2[f] * rsqrtf(var + 1e-5f);
  float b = be2[f] - mean * a;
  float v = x[idx] + fmaf(summed[idx], a, b);
  float r = softplusf_(v);
  x[idx] = r;
  xh[idx] = f2bf(r);
}

__global__ __launch_bounds__(256) void pool_kernel(
    const float* __restrict__ x, const int* __restrict__ cidx,
    float* __restrict__ crys, float* __restrict__ cnt){
  int idx = blockIdx.x * 256 + threadIdx.x;
  int n = idx >> 6, f = idx & 63;
  int c = cidx[n];
  atomicAdd(&crys[c * FD + f], x[idx]);
  if (f == 0) atomicAdd(&cnt[c], 1.f);
}

__global__ __launch_bounds__(128) void head_kernel(
    const float* __restrict__ crys, const float* __restrict__ cnt,
    const float* __restrict__ W_fc, const float* __restrict__ b_fc,
    const float* __restrict__ W_out, const float* __restrict__ b_out,
    void* __restrict__ out, const int* __restrict__ flag){
  __shared__ float p_s[FD];
  __shared__ float red_s[HD];
  int c = blockIdx.x, tid = threadIdx.x;
  if (tid < FD){
    float ct = fmaxf(cnt[c], 1.f);
    p_s[tid] = softplusf_(crys[c * FD + tid] / ct);
  }
  __syncthreads();
  float acc = b_fc[tid];
  for (int k = 0; k < FD; k++)
    acc = fmaf(p_s[k], W_fc[k * HD + tid], acc);
  float h = softplusf_(acc);
  red_s[tid] = h * W_out[tid];
  __syncthreads();
  for (int s = HD / 2; s > 0; s >>= 1){
    if (tid < s) red_s[tid] += red_s[tid + s];
    __syncthreads();
  }
  if (tid == 0){
    float r = red_s[0] + b_out[0];
    if (*flag) ((u16*)out)[c] = f2bf(r);
    else       ((float*)out)[c] = r;
  }
}

extern "C" void kernel_launch(void* const* d_in, const int* in_sizes, int n_in,
                              void* d_out, int out_size, void* d_ws, size_t ws_size,
                              hipStream_t stream){
  if (ws_size < WS_NEED_BYTES) return;  // diagnostic: leaves d_out zeroed
  const bool full = (ws_size >= WS_FULL_BYTES);
  const void* atom_fea = d_in[0];
  const void* nbr_fea  = d_in[1];
  const int* nbr_idx   = (const int*)d_in[2];
  const int* cidx      = (const int*)d_in[3];

  float* ws     = (float*)d_ws;
  float* x      = ws + OFF_X;
  u16*   xh     = (u16*)(ws + OFF_XH);
  float* summed = ws + OFF_SUMMED;
  float* sum1   = ws + OFF_STATS;
  float* sq1    = sum1 + 128;
  float* sum2   = sq1 + 128;
  float* sq2    = sum2 + 64;
  float* crys   = ws + OFF_CRYS;
  float* cnt    = ws + OFF_CNT;
  float* wc     = ws + OFF_WCONV;
  u16*   wbf    = (u16*)(ws + OFF_WBF);
  int*   flag   = (int*)(ws + OFF_FLAG);
  u16*   bpad   = (u16*)(ws + OFF_BPAD);

  detect_kernel<<<1, 64, 0, stream>>>((const u16*)nbr_fea, flag);
  CvtArgs ca;
  const int srcidx[12] = {4,5,6,7,8,9,10,11,12,13,14,15};
  const int starts[13] = {W_EMB_O, B_EMB_O, W_FULL_O, B_FULL_O, G1_O, BE1_O,
                          G2_O, BE2_O, W_FC_O, B_FC_O, W_OUT_O, B_OUT_O, WC_TOTAL};
  for (int i = 0; i < 12; i++){ ca.src[i] = d_in[srcidx[i]]; ca.start[i] = starts[i]; }
  ca.start[12] = WC_TOTAL;
  cvt_all_kernel<<<(WC_TOTAL + 255) / 256, 256, 0, stream>>>(ca, wc, flag);
  build_bfrag<<<(9216 + 255) / 256, 256, 0, stream>>>(wc + W_FULL_O, wbf);
  if (full) bond_prep<<<NSUP, 256, 0, stream>>>(nbr_fea, bpad, flag);

  embed_kernel<<<NATOM / 4, 256, 0, stream>>>(atom_fea, wc + W_EMB_O, wc + B_EMB_O,
                                              x, xh, flag);
  const int LDS_STATS_S = 11264 + 2 * 128 * 4;                  // 12288
  const int LDS_ACT_S   = 11264 + (48 * GS + 128) * 4;          // 37120
  const int LDS_STATS_F = 6144 + 2 * 128 * 4;                   // 7168
  const int LDS_ACT_F   = 6144 + (48 * GS + 128) * 4;           // 32000
  for (int i = 0; i < 3; i++){
    const u16* wbf_l = wbf + (size_t)i * 3072 * 8;
    hipMemsetAsync(sum1, 0, 384 * sizeof(float), stream);
    if (full){
      conv_share<0><<<3000, 256, LDS_STATS_S, stream>>>(xh, bpad, nbr_idx,
          wbf_l, wc + B_FULL_O + i * F2D, sum1, sq1, wc + G1_O + i * F2D,
          wc + BE1_O + i * F2D, summed, sum1, sq1);
      conv_share<1><<<3000, 256, LDS_ACT_S, stream>>>(xh, bpad, nbr_idx,
          wbf_l, wc + B_FULL_O + i * F2D, sum1, sq1, wc + G1_O + i * F2D,
          wc + BE1_O + i * F2D, summed, sum2, sq2);
    } else {
      conv_mfma<0><<<3000, 256, LDS_STATS_F, stream>>>(xh, nbr_fea, nbr_idx,
          wbf_l, wc + B_FULL_O + i * F2D, sum1, sq1, wc + G1_O + i * F2D,
          wc + BE1_O + i * F2D, summed, sum1, sq1, flag);
      conv_mfma<1><<<3000, 256, LDS_ACT_F, stream>>>(xh, nbr_fea, nbr_idx,
          wbf_l, wc + B_FULL_O + i * F2D, sum1, sq1, wc + G1_O + i * F2D,
          wc + BE1_O + i * F2D, summed, sum2, sq2, flag);
    }
    update_x_kernel<<<(NATOM * FD) / 256, 256, 0, stream>>>(x, xh, summed, sum2, sq2,
        wc + G2_O + i * FD, wc + BE2_O + i * FD);
  }
  hipMemsetAsync(crys, 0, (NCRY * FD + NCRY) * sizeof(float), stream);
  pool_kernel<<<(NATOM * FD) / 256, 256, 0, stream>>>(x, cidx, crys, cnt);
  head_kernel<<<NCRY, 128, 0, stream>>>(crys, cnt, wc + W_FC_O, wc + B_FC_O,
      wc + W_OUT_O, wc + B_OUT_O, d_out, flag);
}

// Round 9
// 980.757 us; speedup vs baseline: 1.5140x; 1.0182x over previous
//
#include <hip/hip_runtime.h>
#include <hip/hip_bf16.h>

// CGCNN forward, MFMA conv GEMM (R17).
//   g[e,:] = [x[n(e)] | x[nb(e)] | bond(e)] @ Wf + b  (K=169 pad 192, N=128)
// R17 vs R16 (107us/disp, occupancy 33%, 3 blocks/CU): the 25KB gbuf caps
// residency; stage-latency can't be covered by 3 blocks. R17 eliminates gbuf
// via two mapping changes (consume-side addressing = R16-verified, untouched):
//   1. col remap: wave w computes filter col f=w*16+nloc (t2=0) and core col
//      64+f (t2=1) -> (u,v) pair is thread-local (only Bf tile select + bias/
//      BN-coef indices change).
//   2. edge permutation: position (et,tr) holds edge (atom=tr>>2, m=et*4+
//      (tr&3)) -> thread (q,.)'s D-rows across ets = atom q's 12 edges ->
//      p-sum is ONE register. Changes ONLY staging rA/rB + bond_prep row.
// ACT phase becomes 12 register-local VALU ops; NO gbuf, NO mid-barriers.
// LDS ~12KB both variants -> 8 blocks/CU at VGPR 60 ((256,3) kept, no
// allocator games). Stats sums are row-order-invariant -> permutation-safe.
// Canary: WRITE 16.5MB(ACT)/~1MB(stats); occupancy >= 60%.
// R7 LDS-staging fallback kept for ws_size < 108.5 MB.

#define NATOM 60000
#define MNBR  12
#define F0D   92
#define FBD   41
#define FD    64
#define F2D   128
#define NCRY  2000
#define HD    128
#define NSUP  15000          // 720000 edges / 48
#define GS    132            // gbuf row stride (fallback only)

// ws layout (float units)
#define OFF_X      0ull          // 3,840,000 f32
#define OFF_XH     3840000ull    // 3,840,000 u16
#define OFF_SUMMED 5760000ull    // 3,840,000 f32
#define OFF_STATS  9600000ull    // sum1[128] sq1[128] sum2[64] sq2[64]
#define OFF_CRYS   9600384ull
#define OFF_CNT    9728384ull
#define OFF_WCONV  9730384ull    // 80,833 f32
#define OFF_WBF    9811220ull    // 73,728 u16 = 36,864 f slots
#define OFF_FLAG   9848084ull
#define WS_NEED_BYTES (9848085ull * 4ull)
#define OFF_BPAD   9848088ull    // 34,560,000 u16 = 17,280,000 f slots (16B aligned)
#define WS_FULL_BYTES ((OFF_BPAD + 17280000ull) * 4ull)   // 108,512,352

// offsets inside wconv
#define W_EMB_O  0
#define B_EMB_O  5888
#define W_FULL_O 5952
#define B_FULL_O 70848
#define G1_O     71232
#define BE1_O    71616
#define G2_O     72000
#define BE2_O    72192
#define W_FC_O   72384
#define B_FC_O   80576
#define W_OUT_O  80704
#define B_OUT_O  80832
#define WC_TOTAL 80833

typedef unsigned short u16;
typedef __attribute__((ext_vector_type(8))) short bf16x8;
typedef __attribute__((ext_vector_type(4))) float f32x4;

__device__ __forceinline__ float bf2f(u16 u){
  union { unsigned int i; float f; } v; v.i = ((unsigned int)u) << 16; return v.f;
}
__device__ __forceinline__ u16 f2bf(float f){
  union { float f; unsigned int i; } v; v.f = f;
  unsigned int x = v.i;
  return (u16)((x + 0x7FFFu + ((x >> 16) & 1u)) >> 16);
}
__device__ __forceinline__ float softplusf_(float x){
  return fmaxf(x, 0.f) + log1pf(expf(-fabsf(x)));
}
__device__ __forceinline__ float softplus_fast(float x){
  return fmaxf(x, 0.f) + __logf(1.f + __expf(-fabsf(x)));
}
__device__ __forceinline__ float sigmoid_fast(float x){
  return __builtin_amdgcn_rcpf(1.f + __expf(-x));
}

__global__ __launch_bounds__(64) void detect_kernel(
    const u16* __restrict__ data, int* __restrict__ flag){
  int tid = threadIdx.x;
  float v = bf2f(data[tid * 2]);
  float av = fabsf(v);
  bool sane = (av > 1e-6f) && (av < 100.f);
  unsigned long long m = __ballot(sane);
  if (tid == 0) *flag = (__popcll(m) >= 32) ? 1 : 0;
}

struct CvtArgs {
  const void* src[12];
  int start[13];
};

__global__ __launch_bounds__(256) void cvt_all_kernel(
    CvtArgs a, float* __restrict__ dst, const int* __restrict__ flag){
  int i = blockIdx.x * 256 + threadIdx.x;
  if (i >= WC_TOTAL) return;
  int r = 0;
  while (i >= a.start[r + 1]) r++;
  int rel = i - a.start[r];
  if (*flag) dst[i] = bf2f(((const u16*)a.src[r])[rel]);
  else       dst[i] = ((const float*)a.src[r])[rel];
}

__global__ __launch_bounds__(256) void build_bfrag(
    const float* __restrict__ wfull, u16* __restrict__ wbf){
  int t = blockIdx.x * 256 + threadIdx.x;
  if (t >= 3 * 6 * 8 * 64) return;
  int lane = t & 63, nt = (t >> 6) & 7, c = (t >> 9) % 6, layer = t / 3072;
  int q = lane >> 4, nloc = lane & 15;
  u16 vals[8];
  #pragma unroll
  for (int i = 0; i < 8; i++){
    int k = c * 32 + q * 8 + i;
    float v = (k < 169) ? wfull[layer * 169 * F2D + k * F2D + nt * 16 + nloc] : 0.f;
    vals[i] = f2bf(v);
  }
  *(uint4*)&wbf[(size_t)t * 8] = *(uint4*)vals;
}

// One-time repack, FRAGMENT-MAJOR per supertile (288 16B slots) with the R17
// edge permutation: position (et, tr) <- local edge (tr>>2)*12 + et*4 + (tr&3).
//   slot j: et=j/96, jj=j%96
//     jj<64 : chunk4 — l=jj,    tr=l&15, feats (l>>4)*8..+7
//     jj>=64: chunk5 — l=jj-64, tr=l&15, feats 32+(l>>4)*8..+7
__global__ __launch_bounds__(256) void bond_prep(
    const void* __restrict__ nbr_fea, u16* __restrict__ bond_pad,
    const int* __restrict__ flag){
  __shared__ __align__(16) char sm[7872];
  u16*   lb_u = (u16*)sm;
  float* lb_f = (float*)sm;
  int s = blockIdx.x, tid = threadIdx.x;
  const int isbf = *flag;
  if (isbf){
    const uint4* src = (const uint4*)((const u16*)nbr_fea + (size_t)s * 1968);
    if (tid < 246) ((uint4*)sm)[tid] = src[tid];
  } else {
    const uint4* src = (const uint4*)((const float*)nbr_fea + (size_t)s * 1968);
    for (int t = tid; t < 492; t += 256) ((uint4*)sm)[t] = src[t];
  }
  __syncthreads();
  uint4* outv = (uint4*)(bond_pad + (size_t)s * 2304);
  for (int slot = tid; slot < 288; slot += 256){
    int et = slot / 96, jj = slot - et * 96;
    int l  = (jj < 64) ? jj : (jj - 64);
    int tr = l & 15;
    int row = (tr >> 2) * 12 + et * 4 + (tr & 3);   // permuted local edge
    int kb  = ((jj < 64) ? 0 : 32) + (l >> 4) * 8;
    u16 v[8];
    #pragma unroll
    for (int i = 0; i < 8; i++){
      int k = kb + i;
      v[i] = (k < FBD) ? (isbf ? lb_u[row * FBD + k] : f2bf(lb_f[row * FBD + k])) : (u16)0;
    }
    outv[slot] = *(uint4*)v;
  }
}

__global__ __launch_bounds__(256) void embed_kernel(
    const void* __restrict__ atom_fea, const float* __restrict__ W_emb,
    const float* __restrict__ b_emb, float* __restrict__ x,
    u16* __restrict__ xh, const int* __restrict__ flag){
  int tid = threadIdx.x;
  int n = blockIdx.x * 4 + (tid >> 6);
  int f = tid & 63;
  float acc = b_emb[f];
  if (*flag){
    const u16* arow = (const u16*)atom_fea + n * F0D;
    for (int k = 0; k < F0D; k++)
      acc = fmaf(bf2f(arow[k]), W_emb[k * FD + f], acc);
  } else {
    const float* arow = (const float*)atom_fea + n * F0D;
    for (int k = 0; k < F0D; k++)
      acc = fmaf(arow[k], W_emb[k * FD + f], acc);
  }
  x[n * FD + f] = acc;
  xh[n * FD + f] = f2bf(acc);
}

// ---------------------------------------------------------------------------
// R17: fused shared-A conv pass, no gbuf. LDS stage buffer (11264 B):
//   [0,4608) bond frag-major (permuted rows); [4608,5120) self 4x128B;
//   [5120,11264) nbr frag-major (chunk j: tr=j&15, et=j>>7, kchunk bits 4-6;
//   source row = permuted edge). Consume addressing identical to R16.
// Wave w: filter col cf=w*16+nloc (Bf tile w), core col 64+cf (tile 4+w).
// Thread (q,nloc): D-rows 4q+i across ets = atom q's 12 edges -> pa register.
// ---------------------------------------------------------------------------
template<int ACT>
__global__ __launch_bounds__(256, 3) void conv_fused(
    const u16* __restrict__ xh, const u16* __restrict__ bond_pad,
    const int* __restrict__ nbr_idx, const u16* __restrict__ wbf_l,
    const float* __restrict__ bfull, const float* __restrict__ sum1,
    const float* __restrict__ sq1, const float* __restrict__ g1,
    const float* __restrict__ be1, float* __restrict__ summed,
    float* __restrict__ o_sum, float* __restrict__ o_sq){
  extern __shared__ char smem[];
  char* stg  = smem;                                  // 11264 B
  float* redS = (float*)(smem + 11264);
  float* redQ = redS + (ACT ? 64 : 128);

  const int tid = threadIdx.x;
  const int w = tid >> 6, lane = tid & 63;
  const int q = lane >> 4, nloc = lane & 15;
  const int cf = w * 16 + nloc;          // filter col / t2=0 col

  bf16x8 Bf[6][2];
  const bf16x8* Bv = (const bf16x8*)wbf_l;
  #pragma unroll
  for (int c = 0; c < 6; c++){
    Bf[c][0] = Bv[(c * 8 + w) * 64 + lane];
    Bf[c][1] = Bv[(c * 8 + 4 + w) * 64 + lane];
  }
  const float bias0 = bfull[cf];
  const float bias1 = bfull[64 + cf];

  float A0 = 0.f, B0 = 0.f, A1 = 0.f, B1 = 0.f;
  if (ACT){
    const float invR = 1.f / (float)(NATOM * MNBR);
    float m0 = sum1[cf] * invR;
    float v0 = fmaxf(sq1[cf] * invR - m0 * m0, 0.f);
    A0 = g1[cf] * rsqrtf(v0 + 1e-5f);       B0 = be1[cf] - m0 * A0;
    float m1 = sum1[64 + cf] * invR;
    float v1 = fmaxf(sq1[64 + cf] * invR - m1 * m1, 0.f);
    A1 = g1[64 + cf] * rsqrtf(v1 + 1e-5f);  B1 = be1[64 + cf] - m1 * A1;
  }
  float sAcc0 = 0.f, qAcc0 = 0.f, sAcc1 = 0.f, qAcc1 = 0.f;
  if (tid < (ACT ? 64 : 128)){ redS[tid] = 0.f; redQ[tid] = 0.f; }

  // per-thread staging parameters (R16 formulas + R17 edge permutation)
  const char* xh8   = (const char*)xh;
  const char* bpad8 = (const char*)bond_pad;
  const int jx1 = tid - 64;                    // round-1 nbr chunks [0,192)
  const int rA  = (tid >= 64)
      ? (((jx1 & 15) >> 2) * 12 + (jx1 >> 7) * 4 + (jx1 & 3)) : 0;
  const int cg1 = (tid >= 64) ? ((((jx1 >> 6) & 1) * 4 + ((jx1 >> 4) & 3)) * 16) : 0;
  const int jx2 = tid + 192;                   // round-2 nbr chunks [192,384)
  const int rB  = (tid < 192)
      ? (((jx2 & 15) >> 2) * 12 + (jx2 >> 7) * 4 + (jx2 & 3)) : 0;
  const int cg2 = (tid < 192) ? ((((jx2 >> 6) & 1) * 4 + ((jx2 >> 4) & 3)) * 16) : 0;

  const bf16x8 zero8 = {0,0,0,0,0,0,0,0};

  for (int s = blockIdx.x; s < NSUP; s += gridDim.x){
    // ---- stage: load -> ds_write immediately (transient regs) ----
    {
      int nbA = nbr_idx[s * 48 + rA];
      int nbB = nbr_idx[s * 48 + rB];
      uint4 rb = *(const uint4*)(bpad8 + (size_t)s * 4608 + (size_t)tid * 16);
      const char* p1;
      if (tid < 32)      p1 = bpad8 + (size_t)s * 4608 + (size_t)(tid + 256) * 16;
      else if (tid < 64) p1 = xh8 + (size_t)s * 512 + (size_t)(tid - 32) * 16;
      else               p1 = xh8 + (size_t)nbA * 128 + cg1;
      uint4 r1 = *(const uint4*)p1;
      *(uint4*)(stg + tid * 16) = rb;
      *(uint4*)(stg + 4096 + tid * 16) = r1;
      if (tid < 192){
        uint4 r2 = *(const uint4*)(xh8 + (size_t)nbB * 128 + cg2);
        *(uint4*)(stg + 8192 + tid * 16) = r2;
      }
    }
    __syncthreads();   // stage buffer complete

    // ---- consume: 3 et-groups, both col-halves, fused ACT in registers ----
    float pa = 0.f;
    #pragma unroll
    for (int et = 0; et < 3; et++){
      const char* xs = stg + 4608 + (nloc >> 2) * 128;   // self atom = nloc>>2
      bf16x8 a0 = *(const bf16x8*)(xs + q * 16);
      bf16x8 a1 = *(const bf16x8*)(xs + 64 + q * 16);
      bf16x8 a2 = *(const bf16x8*)(stg + 5120 + (et * 128 + lane) * 16);
      bf16x8 a3 = *(const bf16x8*)(stg + 5120 + (et * 128 + 64 + lane) * 16);
      bf16x8 a4 = *(const bf16x8*)(stg + (et * 96 + lane) * 16);
      bf16x8 a5 = (lane < 32) ? *(const bf16x8*)(stg + (et * 96 + 64 + lane) * 16)
                              : zero8;
      f32x4 accF = {bias0, bias0, bias0, bias0};
      accF = __builtin_amdgcn_mfma_f32_16x16x32_bf16(a0, Bf[0][0], accF, 0, 0, 0);
      accF = __builtin_amdgcn_mfma_f32_16x16x32_bf16(a1, Bf[1][0], accF, 0, 0, 0);
      accF = __builtin_amdgcn_mfma_f32_16x16x32_bf16(a2, Bf[2][0], accF, 0, 0, 0);
      accF = __builtin_amdgcn_mfma_f32_16x16x32_bf16(a3, Bf[3][0], accF, 0, 0, 0);
      accF = __builtin_amdgcn_mfma_f32_16x16x32_bf16(a4, Bf[4][0], accF, 0, 0, 0);
      accF = __builtin_amdgcn_mfma_f32_16x16x32_bf16(a5, Bf[5][0], accF, 0, 0, 0);
      f32x4 accC = {bias1, bias1, bias1, bias1};
      accC = __builtin_amdgcn_mfma_f32_16x16x32_bf16(a0, Bf[0][1], accC, 0, 0, 0);
      accC = __builtin_amdgcn_mfma_f32_16x16x32_bf16(a1, Bf[1][1], accC, 0, 0, 0);
      accC = __builtin_amdgcn_mfma_f32_16x16x32_bf16(a2, Bf[2][1], accC, 0, 0, 0);
      accC = __builtin_amdgcn_mfma_f32_16x16x32_bf16(a3, Bf[3][1], accC, 0, 0, 0);
      accC = __builtin_amdgcn_mfma_f32_16x16x32_bf16(a4, Bf[4][1], accC, 0, 0, 0);
      accC = __builtin_amdgcn_mfma_f32_16x16x32_bf16(a5, Bf[5][1], accC, 0, 0, 0);
      if (ACT){
        #pragma unroll
        for (int i = 0; i < 4; i++){
          float u = fmaf(accF[i], A0, B0);
          float v = fmaf(accC[i], A1, B1);
          pa = fmaf(sigmoid_fast(u), softplus_fast(v), pa);
        }
      } else {
        sAcc0 += accF[0] + accF[1] + accF[2] + accF[3];
        qAcc0 += accF[0]*accF[0] + accF[1]*accF[1] + accF[2]*accF[2] + accF[3]*accF[3];
        sAcc1 += accC[0] + accC[1] + accC[2] + accC[3];
        qAcc1 += accC[0]*accC[0] + accC[1]*accC[1] + accC[2]*accC[2] + accC[3]*accC[3];
      }
    }
    if (ACT){
      // thread (q,nloc,w) owns p[atom q][col cf] exactly
      summed[((size_t)s * 4 + q) * 64 + cf] = pa;
      sAcc0 += pa;  qAcc0 = fmaf(pa, pa, qAcc0);
    }
    __syncthreads();   // stage free for next supertile
  }

  if (ACT){
    atomicAdd(&redS[cf], sAcc0);
    atomicAdd(&redQ[cf], qAcc0);
    __syncthreads();
    if (tid < 64){ atomicAdd(&o_sum[tid], redS[tid]); atomicAdd(&o_sq[tid], redQ[tid]); }
  } else {
    atomicAdd(&redS[cf], sAcc0);       atomicAdd(&redQ[cf], qAcc0);
    atomicAdd(&redS[64 + cf], sAcc1);  atomicAdd(&redQ[64 + cf], qAcc1);
    __syncthreads();
    if (tid < 128){ atomicAdd(&o_sum[tid], redS[tid]); atomicAdd(&o_sq[tid], redQ[tid]); }
  }
}

// R7 fallback conv pass (small-ws path; reads raw nbr_fea, no bond_pad).
template<int ACT>
__global__ __launch_bounds__(256, 3) void conv_mfma(
    const u16* __restrict__ xh, const void* __restrict__ nbr_fea,
    const int* __restrict__ nbr_idx, const u16* __restrict__ wbf_l,
    const float* __restrict__ bfull, const float* __restrict__ sum1,
    const float* __restrict__ sq1, const float* __restrict__ g1,
    const float* __restrict__ be1, float* __restrict__ summed,
    float* __restrict__ o_sum, float* __restrict__ o_sq,
    const int* __restrict__ flag){
  extern __shared__ char smem[];
  u16*   fragA = (u16*)smem;                      // 6*512 u16
  float* gbuf  = (float*)(smem + 6144);           // ACT only: 48*GS
  float* redS  = ACT ? (gbuf + 48 * GS) : (float*)(smem + 6144);
  float* redQ  = redS + (ACT ? 64 : 128);

  const int tid = threadIdx.x;
  const int w = tid >> 6, lane = tid & 63;
  const int q = lane >> 4, nloc = lane & 15, q8 = q * 8;
  const int isbf = *flag;

  bf16x8 Bf[6][2];
  const bf16x8* Bv = (const bf16x8*)wbf_l;
  #pragma unroll
  for (int c = 0; c < 6; c++)
    #pragma unroll
    for (int t2 = 0; t2 < 2; t2++)
      Bf[c][t2] = Bv[(c * 8 + w * 2 + t2) * 64 + lane];
  float bias0 = bfull[w * 32 + nloc];
  float bias1 = bfull[w * 32 + 16 + nloc];

  float A0 = 0.f, B0 = 0.f, A1 = 0.f, B1 = 0.f;
  if (ACT){
    const float invR = 1.f / (float)(NATOM * MNBR);
    float m0 = sum1[lane] * invR;
    float v0 = fmaxf(sq1[lane] * invR - m0 * m0, 0.f);
    A0 = g1[lane] * rsqrtf(v0 + 1e-5f);  B0 = be1[lane] - m0 * A0;
    float m1 = sum1[64 + lane] * invR;
    float v1 = fmaxf(sq1[64 + lane] * invR - m1 * m1, 0.f);
    A1 = g1[64 + lane] * rsqrtf(v1 + 1e-5f);  B1 = be1[64 + lane] - m1 * A1;
  }
  float sAcc0 = 0.f, sAcc1 = 0.f, qAcc0 = 0.f, qAcc1 = 0.f;
  if (tid < (ACT ? 64 : 128)){ redS[tid] = 0.f; redQ[tid] = 0.f; }

  const bf16x8* xv = (const bf16x8*)xh;
  for (int s = blockIdx.x; s < NSUP; s += gridDim.x){
    int e0 = s * 48 + nloc;
    int nb0 = nbr_idx[e0], nb1 = nbr_idx[e0 + 16], nb2 = nbr_idx[e0 + 32];
    bf16x8 Af[3][6];
    if (w < 3){
      size_t eg = (size_t)(s * 48 + w * 16 + nloc);
      u16 v4[8], v5[8];
      if (isbf){
        const u16* br = (const u16*)nbr_fea + eg * 41;
        #pragma unroll
        for (int i = 0; i < 8; i++) v4[i] = br[q8 + i];
        #pragma unroll
        for (int i = 0; i < 8; i++){
          int k5 = 32 + q8 + i;
          v5[i] = (k5 < 41) ? br[k5] : (u16)0;
        }
      } else {
        const float* br = (const float*)nbr_fea + eg * 41;
        #pragma unroll
        for (int i = 0; i < 8; i++) v4[i] = f2bf(br[q8 + i]);
        #pragma unroll
        for (int i = 0; i < 8; i++){
          int k5 = 32 + q8 + i;
          v5[i] = (k5 < 41) ? f2bf(br[k5]) : (u16)0;
        }
      }
      *(uint4*)&fragA[(w * 2 + 0) * 512 + lane * 8] = *(uint4*)v4;
      *(uint4*)&fragA[(w * 2 + 1) * 512 + lane * 8] = *(uint4*)v5;
    }
    __syncthreads();
    #pragma unroll
    for (int et = 0; et < 3; et++){
      int nb = (et == 0) ? nb0 : (et == 1) ? nb1 : nb2;
      int na = s * 4 + (et * 16 + nloc) / 12;
      Af[et][0] = xv[na * 8 + q];
      Af[et][1] = xv[na * 8 + 4 + q];
      Af[et][2] = xv[nb * 8 + q];
      Af[et][3] = xv[nb * 8 + 4 + q];
      Af[et][4] = *(bf16x8*)&fragA[(et * 2 + 0) * 512 + lane * 8];
      Af[et][5] = *(bf16x8*)&fragA[(et * 2 + 1) * 512 + lane * 8];
    }
    #pragma unroll
    for (int et = 0; et < 3; et++){
      #pragma unroll
      for (int t2 = 0; t2 < 2; t2++){
        float bs = t2 ? bias1 : bias0;
        f32x4 acc = {bs, bs, bs, bs};
        acc = __builtin_amdgcn_mfma_f32_16x16x32_bf16(Af[et][0], Bf[0][t2], acc, 0, 0, 0);
        acc = __builtin_amdgcn_mfma_f32_16x16x32_bf16(Af[et][1], Bf[1][t2], acc, 0, 0, 0);
        acc = __builtin_amdgcn_mfma_f32_16x16x32_bf16(Af[et][2], Bf[2][t2], acc, 0, 0, 0);
        acc = __builtin_amdgcn_mfma_f32_16x16x32_bf16(Af[et][3], Bf[3][t2], acc, 0, 0, 0);
        acc = __builtin_amdgcn_mfma_f32_16x16x32_bf16(Af[et][4], Bf[4][t2], acc, 0, 0, 0);
        acc = __builtin_amdgcn_mfma_f32_16x16x32_bf16(Af[et][5], Bf[5][t2], acc, 0, 0, 0);
        if (ACT){
          int col = w * 32 + t2 * 16 + nloc;
          int r0 = et * 16 + q * 4;
          gbuf[(r0 + 0) * GS + col] = acc[0];
          gbuf[(r0 + 1) * GS + col] = acc[1];
          gbuf[(r0 + 2) * GS + col] = acc[2];
          gbuf[(r0 + 3) * GS + col] = acc[3];
        } else {
          float ss = acc[0] + acc[1] + acc[2] + acc[3];
          float qq = acc[0]*acc[0] + acc[1]*acc[1] + acc[2]*acc[2] + acc[3]*acc[3];
          if (t2){ sAcc1 += ss; qAcc1 += qq; } else { sAcc0 += ss; qAcc0 += qq; }
        }
      }
    }
    if (ACT){
      __syncthreads();
      float p = 0.f;
      #pragma unroll
      for (int m = 0; m < 12; m++){
        int el = w * 12 + m;
        float u = fmaf(gbuf[el * GS + lane],      A0, B0);
        float v = fmaf(gbuf[el * GS + 64 + lane], A1, B1);
        p = fmaf(sigmoid_fast(u), softplus_fast(v), p);
      }
      summed[(s * 4 + w) * 64 + lane] = p;
      sAcc0 += p;  qAcc0 = fmaf(p, p, qAcc0);
    }
    __syncthreads();
  }
  if (ACT){
    atomicAdd(&redS[lane], sAcc0);
    atomicAdd(&redQ[lane], qAcc0);
    __syncthreads();
    if (tid < 64){ atomicAdd(&o_sum[tid], redS[tid]); atomicAdd(&o_sq[tid], redQ[tid]); }
  } else {
    int c0 = w * 32 + nloc;
    atomicAdd(&redS[c0], sAcc0);       atomicAdd(&redQ[c0], qAcc0);
    atomicAdd(&redS[c0 + 16], sAcc1);  atomicAdd(&redQ[c0 + 16], qAcc1);
    __syncthreads();
    if (tid < 128){ atomicAdd(&o_sum[tid], redS[tid]); atomicAdd(&o_sq[tid], redQ[tid]); }
  }
}

__global__ __launch_bounds__(256) void update_x_kernel(
    float* __restrict__ x, u16* __restrict__ xh,
    const float* __restrict__ summed,
    const float* __restrict__ sum2, const float* __restrict__ sq2,
    const float* __restrict__ g2, const float* __restrict__ be2){
  int idx = blockIdx.x * 256 + threadIdx.x;
  int f = idx & 63;
  const float invN = 1.f / (float)NATOM;
  float mean = sum2[f] * invN;
  float var  = fmaxf(sq2[f] * invN - mean * mean, 0.f);
  float a = g2[f] * rsqrtf(var + 1e-5f);
  float b = be2[f] - mean * a;
  float v = x[idx] + fmaf(summed[idx], a, b);
  float r = softplusf_(v);
  x[idx] = r;
  xh[idx] = f2bf(r);
}

__global__ __launch_bounds__(256) void pool_kernel(
    const float* __restrict__ x, const int* __restrict__ cidx,
    float* __restrict__ crys, float* __restrict__ cnt){
  int idx = blockIdx.x * 256 + threadIdx.x;
  int n = idx >> 6, f = idx & 63;
  int c = cidx[n];
  atomicAdd(&crys[c * FD + f], x[idx]);
  if (f == 0) atomicAdd(&cnt[c], 1.f);
}

__global__ __launch_bounds__(128) void head_kernel(
    const float* __restrict__ crys, const float* __restrict__ cnt,
    const float* __restrict__ W_fc, const float* __restrict__ b_fc,
    const float* __restrict__ W_out, const float* __restrict__ b_out,
    void* __restrict__ out, const int* __restrict__ flag){
  __shared__ float p_s[FD];
  __shared__ float red_s[HD];
  int c = blockIdx.x, tid = threadIdx.x;
  if (tid < FD){
    float ct = fmaxf(cnt[c], 1.f);
    p_s[tid] = softplusf_(crys[c * FD + tid] / ct);
  }
  __syncthreads();
  float acc = b_fc[tid];
  for (int k = 0; k < FD; k++)
    acc = fmaf(p_s[k], W_fc[k * HD + tid], acc);
  float h = softplusf_(acc);
  red_s[tid] = h * W_out[tid];
  __syncthreads();
  for (int s = HD / 2; s > 0; s >>= 1){
    if (tid < s) red_s[tid] += red_s[tid + s];
    __syncthreads();
  }
  if (tid == 0){
    float r = red_s[0] + b_out[0];
    if (*flag) ((u16*)out)[c] = f2bf(r);
    else       ((float*)out)[c] = r;
  }
}

extern "C" void kernel_launch(void* const* d_in, const int* in_sizes, int n_in,
                              void* d_out, int out_size, void* d_ws, size_t ws_size,
                              hipStream_t stream){
  if (ws_size < WS_NEED_BYTES) return;  // diagnostic: leaves d_out zeroed
  const bool full = (ws_size >= WS_FULL_BYTES);
  const void* atom_fea = d_in[0];
  const void* nbr_fea  = d_in[1];
  const int* nbr_idx   = (const int*)d_in[2];
  const int* cidx      = (const int*)d_in[3];

  float* ws     = (float*)d_ws;
  float* x      = ws + OFF_X;
  u16*   xh     = (u16*)(ws + OFF_XH);
  float* summed = ws + OFF_SUMMED;
  float* sum1   = ws + OFF_STATS;
  float* sq1    = sum1 + 128;
  float* sum2   = sq1 + 128;
  float* sq2    = sum2 + 64;
  float* crys   = ws + OFF_CRYS;
  float* cnt    = ws + OFF_CNT;
  float* wc     = ws + OFF_WCONV;
  u16*   wbf    = (u16*)(ws + OFF_WBF);
  int*   flag   = (int*)(ws + OFF_FLAG);
  u16*   bpad   = (u16*)(ws + OFF_BPAD);

  detect_kernel<<<1, 64, 0, stream>>>((const u16*)nbr_fea, flag);
  CvtArgs ca;
  const int srcidx[12] = {4,5,6,7,8,9,10,11,12,13,14,15};
  const int starts[13] = {W_EMB_O, B_EMB_O, W_FULL_O, B_FULL_O, G1_O, BE1_O,
                          G2_O, BE2_O, W_FC_O, B_FC_O, W_OUT_O, B_OUT_O, WC_TOTAL};
  for (int i = 0; i < 12; i++){ ca.src[i] = d_in[srcidx[i]]; ca.start[i] = starts[i]; }
  ca.start[12] = WC_TOTAL;
  cvt_all_kernel<<<(WC_TOTAL + 255) / 256, 256, 0, stream>>>(ca, wc, flag);
  build_bfrag<<<(9216 + 255) / 256, 256, 0, stream>>>(wc + W_FULL_O, wbf);
  if (full) bond_prep<<<NSUP, 256, 0, stream>>>(nbr_fea, bpad, flag);

  embed_kernel<<<NATOM / 4, 256, 0, stream>>>(atom_fea, wc + W_EMB_O, wc + B_EMB_O,
                                              x, xh, flag);
  const int LDS_STATS_N = 11264 + 2 * 128 * 4;                  // 12288
  const int LDS_ACT_N   = 11264 + 2 * 64 * 4;                   // 11776
  const int LDS_STATS_F = 6144 + 2 * 128 * 4;                   // 7168
  const int LDS_ACT_F   = 6144 + (48 * GS + 128) * 4;           // 32000
  for (int i = 0; i < 3; i++){
    const u16* wbf_l = wbf + (size_t)i * 3072 * 8;
    hipMemsetAsync(sum1, 0, 384 * sizeof(float), stream);
    if (full){
      conv_fused<0><<<3000, 256, LDS_STATS_N, stream>>>(xh, bpad, nbr_idx,
          wbf_l, wc + B_FULL_O + i * F2D, sum1, sq1, wc + G1_O + i * F2D,
          wc + BE1_O + i * F2D, summed, sum1, sq1);
      conv_fused<1><<<3000, 256, LDS_ACT_N, stream>>>(xh, bpad, nbr_idx,
          wbf_l, wc + B_FULL_O + i * F2D, sum1, sq1, wc + G1_O + i * F2D,
          wc + BE1_O + i * F2D, summed, sum2, sq2);
    } else {
      conv_mfma<0><<<3000, 256, LDS_STATS_F, stream>>>(xh, nbr_fea, nbr_idx,
          wbf_l, wc + B_FULL_O + i * F2D, sum1, sq1, wc + G1_O + i * F2D,
          wc + BE1_O + i * F2D, summed, sum1, sq1, flag);
      conv_mfma<1><<<3000, 256, LDS_ACT_F, stream>>>(xh, nbr_fea, nbr_idx,
          wbf_l, wc + B_FULL_O + i * F2D, sum1, sq1, wc + G1_O + i * F2D,
          wc + BE1_O + i * F2D, summed, sum2, sq2, flag);
    }
    update_x_kernel<<<(NATOM * FD) / 256, 256, 0, stream>>>(x, xh, summed, sum2, sq2,
        wc + G2_O + i * FD, wc + BE2_O + i * FD);
  }
  hipMemsetAsync(crys, 0, (NCRY * FD + NCRY) * sizeof(float), stream);
  pool_kernel<<<(NATOM * FD) / 256, 256, 0, stream>>>(x, cidx, crys, cnt);
  head_kernel<<<NCRY, 128, 0, stream>>>(crys, cnt, wc + W_FC_O, wc + B_FC_O,
      wc + W_OUT_O, wc + B_OUT_O, d_out, flag);
}